// Round 1
// baseline (2526.156 us; speedup 1.0000x reference)
//
#include <hip/hip_runtime.h>
#include <math.h>

#define BSZ_  4
#define SEQ_  1024
#define NH_   32
#define NKVH_ 8
#define HD_   128
#define DIM_  4096
#define NTOK_ (BSZ_ * SEQ_)   // 4096 tokens

typedef float  floatx4 __attribute__((ext_vector_type(4)));
typedef __bf16 bf16x8  __attribute__((ext_vector_type(8)));

__device__ __forceinline__ unsigned short f2bf_bits(float f) {
  unsigned int u = __float_as_uint(f);
  u += 0x7FFFu + ((u >> 16) & 1u);   // round-to-nearest-even
  return (unsigned short)(u >> 16);
}

// ---------------------------------------------------------------------------
// Generic row-major GEMM: C[M][N] = A[M][K] @ B[K][N], fp32 in/out, bf16 MFMA.
// Tile 128x128x32. 256 threads = 4 waves; wave w owns 64x64 quadrant
// (mw=(w>>1)*64, nw=(w&1)*64) as 4x4 MFMA tiles of 16x16.
// M,N multiples of 128; K multiple of 32 (true for all our shapes).
// ---------------------------------------------------------------------------
__global__ __launch_bounds__(256)
void gemm_rrr_bf16(const float* __restrict__ A, const float* __restrict__ Bm,
                   float* __restrict__ C, int M, int N, int K)
{
  // +8 pad breaks power-of-2 row stride for fragment reads; rows stay 16B-aligned.
  __shared__ __align__(16) unsigned short As[128][40];   // [m][k] bf16
  __shared__ __align__(16) unsigned short Bs[128][40];   // [n][k] bf16 (B transposed)

  const int tid  = threadIdx.x;
  const int bm   = blockIdx.y * 128;
  const int bn   = blockIdx.x * 128;
  const int w    = tid >> 6;
  const int lane = tid & 63;
  const int l16  = lane & 15;
  const int quad = lane >> 4;
  const int mw   = (w >> 1) * 64;
  const int nw   = (w & 1) * 64;

  floatx4 acc[4][4];
#pragma unroll
  for (int i = 0; i < 4; i++)
#pragma unroll
    for (int j = 0; j < 4; j++) acc[i][j] = (floatx4){0.f, 0.f, 0.f, 0.f};

  for (int k0 = 0; k0 < K; k0 += 32) {
    // ---- stage A tile: 128 rows x 32 k  (1024 float4 loads, 4 per thread)
#pragma unroll
    for (int it = 0; it < 4; it++) {
      int idx = tid + it * 256;        // 0..1023
      int row = idx >> 3;              // 8 float4 per row
      int kq  = idx & 7;
      const float4 va = *(const float4*)&A[(size_t)(bm + row) * K + k0 + kq * 4];
      As[row][kq * 4 + 0] = f2bf_bits(va.x);
      As[row][kq * 4 + 1] = f2bf_bits(va.y);
      As[row][kq * 4 + 2] = f2bf_bits(va.z);
      As[row][kq * 4 + 3] = f2bf_bits(va.w);
    }
    // ---- stage B tile transposed: B[k0+kk][bn+n] -> Bs[n][kk]
#pragma unroll
    for (int it = 0; it < 4; it++) {
      int idx = tid + it * 256;        // 0..1023
      int kk  = idx >> 5;              // 0..31
      int nq  = idx & 31;              // float4 index along n
      const float4 vb = *(const float4*)&Bm[(size_t)(k0 + kk) * N + bn + nq * 4];
      Bs[nq * 4 + 0][kk] = f2bf_bits(vb.x);
      Bs[nq * 4 + 1][kk] = f2bf_bits(vb.y);
      Bs[nq * 4 + 2][kk] = f2bf_bits(vb.z);
      Bs[nq * 4 + 3][kk] = f2bf_bits(vb.w);
    }
    __syncthreads();

    bf16x8 af[4], bf[4];
#pragma unroll
    for (int i = 0; i < 4; i++)
      af[i] = *(const bf16x8*)&As[mw + i * 16 + l16][quad * 8];
#pragma unroll
    for (int j = 0; j < 4; j++)
      bf[j] = *(const bf16x8*)&Bs[nw + j * 16 + l16][quad * 8];
#pragma unroll
    for (int i = 0; i < 4; i++)
#pragma unroll
      for (int j = 0; j < 4; j++)
        acc[i][j] = __builtin_amdgcn_mfma_f32_16x16x32_bf16(af[i], bf[j], acc[i][j], 0, 0, 0);
    __syncthreads();
  }

  // ---- epilogue: D[row=quad*4+r][col=l16]
#pragma unroll
  for (int i = 0; i < 4; i++)
#pragma unroll
    for (int j = 0; j < 4; j++)
#pragma unroll
      for (int r = 0; r < 4; r++) {
        int row = bm + mw + i * 16 + quad * 4 + r;
        int col = bn + nw + j * 16 + l16;
        C[(size_t)row * N + col] = acc[i][j][r];
      }
}

// ---------------------------------------------------------------------------
// RoPE in place on (B,S,nh,128) fp32: one thread per even/odd pair.
// shift = log2(64*nh) so pos = (idx >> shift) & (SEQ-1).
// ---------------------------------------------------------------------------
__global__ __launch_bounds__(256)
void rope_kernel(float* __restrict__ t, const float* __restrict__ cosf,
                 const float* __restrict__ sinf, int shift)
{
  int idx = blockIdx.x * 256 + threadIdx.x;  // pair index, grid sized exactly
  int d2  = idx & 63;
  int pos = (idx >> shift) & (SEQ_ - 1);
  float2 p = ((const float2*)t)[idx];
  float cv = cosf[pos * 64 + d2];
  float sv = sinf[pos * 64 + d2];
  float2 o;
  o.x = p.x * cv - p.y * sv;
  o.y = p.x * sv + p.y * cv;
  ((float2*)t)[idx] = o;
}

// ---------------------------------------------------------------------------
// Flash attention (GQA, causal). q:(B,S,32,128) k,v:(B,S,8,128) o:(B,S,32,128)
// Block = 64 q-rows of one (b,h); 4 waves x 16 q-rows. K-tiles of 32 keys.
// QK^T and PV via mfma_f32_16x16x32_bf16; online softmax on C-layout rows.
// ---------------------------------------------------------------------------
__global__ __launch_bounds__(256)
void flash_attn(const float* __restrict__ q, const float* __restrict__ k,
                const float* __restrict__ v, float* __restrict__ o)
{
  const int qt  = blockIdx.x;     // 0..15
  const int h   = blockIdx.y;     // 0..31
  const int b   = blockIdx.z;     // 0..3
  const int kvh = h >> 2;
  const int tid  = threadIdx.x;
  const int w    = tid >> 6;
  const int lane = tid & 63;
  const int l16  = lane & 15;
  const int quad = lane >> 4;
  const int q0   = qt * 64;
  const int qrow_base = q0 + w * 16;

  __shared__ __align__(16) unsigned short Ks[32][136]; // [key][d]  bf16
  __shared__ __align__(16) unsigned short Vt[128][40]; // [d][key]  bf16 (transposed)
  __shared__ __align__(16) unsigned short Ps[4][16][32]; // per-wave P, [q][key] bf16

  const float SCALE = 0.08838834764831845f; // 1/sqrt(128), folded into Q

  // Q fragments in registers: qf[c][j] = Q[qrow_base+l16][c*32 + quad*8 + j]
  bf16x8 qf[4];
  {
    const float* qrow = &q[(((size_t)b * SEQ_ + qrow_base + l16) * NH_ + h) * HD_];
#pragma unroll
    for (int c = 0; c < 4; c++) {
      float4 f0 = *(const float4*)&qrow[c * 32 + quad * 8];
      float4 f1 = *(const float4*)&qrow[c * 32 + quad * 8 + 4];
      union { unsigned short u[8]; bf16x8 vv; } un;
      un.u[0] = f2bf_bits(f0.x * SCALE); un.u[1] = f2bf_bits(f0.y * SCALE);
      un.u[2] = f2bf_bits(f0.z * SCALE); un.u[3] = f2bf_bits(f0.w * SCALE);
      un.u[4] = f2bf_bits(f1.x * SCALE); un.u[5] = f2bf_bits(f1.y * SCALE);
      un.u[6] = f2bf_bits(f1.z * SCALE); un.u[7] = f2bf_bits(f1.w * SCALE);
      qf[c] = un.vv;
    }
  }

  float m_r[4], l_r[4];
  floatx4 oacc[8];
#pragma unroll
  for (int r = 0; r < 4; r++) { m_r[r] = -3.0e38f; l_r[r] = 0.f; }
#pragma unroll
  for (int dt = 0; dt < 8; dt++) oacc[dt] = (floatx4){0.f, 0.f, 0.f, 0.f};

  const int ktiles = (q0 + 64) >> 5;   // causal: keys 0 .. q0+63
  for (int kt = 0; kt < ktiles; kt++) {
    const int kbase = kt * 32;
    // ---- stage K (row-major) and V (transposed) tiles, bf16
#pragma unroll
    for (int it = 0; it < 4; it++) {
      int idx = tid + it * 256;        // 0..1023
      int key = idx >> 5;              // 0..31
      int dq  = idx & 31;              // float4 along d
      size_t base = (((size_t)b * SEQ_ + kbase + key) * NKVH_ + kvh) * HD_ + dq * 4;
      float4 kv4 = *(const float4*)&k[base];
      Ks[key][dq * 4 + 0] = f2bf_bits(kv4.x);
      Ks[key][dq * 4 + 1] = f2bf_bits(kv4.y);
      Ks[key][dq * 4 + 2] = f2bf_bits(kv4.z);
      Ks[key][dq * 4 + 3] = f2bf_bits(kv4.w);
      float4 vv4 = *(const float4*)&v[base];
      Vt[dq * 4 + 0][key] = f2bf_bits(vv4.x);
      Vt[dq * 4 + 1][key] = f2bf_bits(vv4.y);
      Vt[dq * 4 + 2][key] = f2bf_bits(vv4.z);
      Vt[dq * 4 + 3][key] = f2bf_bits(vv4.w);
    }
    __syncthreads();

    // ---- QK^T: S[16q][32keys] as two C-frags
    floatx4 sc0 = (floatx4){0.f, 0.f, 0.f, 0.f};
    floatx4 sc1 = (floatx4){0.f, 0.f, 0.f, 0.f};
#pragma unroll
    for (int c = 0; c < 4; c++) {
      bf16x8 b0 = *(const bf16x8*)&Ks[l16][c * 32 + quad * 8];
      bf16x8 b1 = *(const bf16x8*)&Ks[16 + l16][c * 32 + quad * 8];
      sc0 = __builtin_amdgcn_mfma_f32_16x16x32_bf16(qf[c], b0, sc0, 0, 0, 0);
      sc1 = __builtin_amdgcn_mfma_f32_16x16x32_bf16(qf[c], b1, sc1, 0, 0, 0);
    }

    // ---- online softmax per q-row (row = quad*4+r; 16 lanes share a row)
#pragma unroll
    for (int r = 0; r < 4; r++) {
      int qi = qrow_base + quad * 4 + r;
      float s0 = (kbase + l16      <= qi) ? sc0[r] : -3.0e38f;
      float s1 = (kbase + 16 + l16 <= qi) ? sc1[r] : -3.0e38f;
      float mx = fmaxf(s0, s1);
      mx = fmaxf(mx, __shfl_xor(mx, 1));
      mx = fmaxf(mx, __shfl_xor(mx, 2));
      mx = fmaxf(mx, __shfl_xor(mx, 4));
      mx = fmaxf(mx, __shfl_xor(mx, 8));
      float mnew  = fmaxf(m_r[r], mx);
      float alpha = __expf(m_r[r] - mnew);
      float p0    = __expf(s0 - mnew);
      float p1    = __expf(s1 - mnew);
      float rs = p0 + p1;
      rs += __shfl_xor(rs, 1);
      rs += __shfl_xor(rs, 2);
      rs += __shfl_xor(rs, 4);
      rs += __shfl_xor(rs, 8);
      l_r[r] = l_r[r] * alpha + rs;
      m_r[r] = mnew;
#pragma unroll
      for (int dt = 0; dt < 8; dt++) oacc[dt][r] *= alpha;
      // C-layout -> LDS for A-layout reload (per-wave patch, no block barrier)
      Ps[w][quad * 4 + r][l16]      = f2bf_bits(p0);
      Ps[w][quad * 4 + r][16 + l16] = f2bf_bits(p1);
    }

    // ---- PV: A = P[16q][32keys] (A-layout), B = Vt => O += P@V
    bf16x8 pf = *(const bf16x8*)&Ps[w][l16][quad * 8];
#pragma unroll
    for (int dt = 0; dt < 8; dt++) {
      bf16x8 vf = *(const bf16x8*)&Vt[dt * 16 + l16][quad * 8];
      oacc[dt] = __builtin_amdgcn_mfma_f32_16x16x32_bf16(pf, vf, oacc[dt], 0, 0, 0);
    }
    __syncthreads();
  }

  // ---- normalize + write O rows
#pragma unroll
  for (int r = 0; r < 4; r++) {
    float inv = 1.0f / l_r[r];
    int qi = qrow_base + quad * 4 + r;
    float* orow = &o[(((size_t)b * SEQ_ + qi) * NH_ + h) * HD_];
#pragma unroll
    for (int dt = 0; dt < 8; dt++)
      orow[dt * 16 + l16] = oacc[dt][r] * inv;
  }
}

// ---------------------------------------------------------------------------
extern "C" void kernel_launch(void* const* d_in, const int* in_sizes, int n_in,
                              void* d_out, int out_size, void* d_ws, size_t ws_size,
                              hipStream_t stream)
{
  const float* x  = (const float*)d_in[0];
  const float* wq = (const float*)d_in[1];
  const float* wk = (const float*)d_in[2];
  const float* wv = (const float*)d_in[3];
  const float* wo = (const float*)d_in[4];
  const float* fc = (const float*)d_in[5];
  const float* fs = (const float*)d_in[6];
  // d_in[7] causal_mask, d_in[8] fixed_point_iter, d_in[9] start_pos: unused
  float* out = (float*)d_out;

  float* qb = (float*)d_ws;                              // 4096 x 4096
  float* kb = qb + (size_t)NTOK_ * DIM_;                 // 4096 x 1024
  float* vb = kb + (size_t)NTOK_ * NKVH_ * HD_;          // 4096 x 1024
  float* ab = vb + (size_t)NTOK_ * NKVH_ * HD_;          // 4096 x 4096
  // ws needed: 160 MB fp32 intermediates

  dim3 blk(256);
  gemm_rrr_bf16<<<dim3(DIM_ / 128, NTOK_ / 128), blk, 0, stream>>>(x, wq, qb, NTOK_, DIM_, DIM_);
  gemm_rrr_bf16<<<dim3((NKVH_ * HD_) / 128, NTOK_ / 128), blk, 0, stream>>>(x, wk, kb, NTOK_, NKVH_ * HD_, DIM_);
  gemm_rrr_bf16<<<dim3((NKVH_ * HD_) / 128, NTOK_ / 128), blk, 0, stream>>>(x, wv, vb, NTOK_, NKVH_ * HD_, DIM_);

  rope_kernel<<<(NTOK_ * NH_ * HD_ / 2) / 256, blk, 0, stream>>>(qb, fc, fs, 11);   // 64*32 = 2048 -> shift 11
  rope_kernel<<<(NTOK_ * NKVH_ * HD_ / 2) / 256, blk, 0, stream>>>(kb, fc, fs, 9);  // 64*8  = 512  -> shift 9

  flash_attn<<<dim3(SEQ_ / 64, NH_, BSZ_), blk, 0, stream>>>(qb, kb, vb, ab);

  gemm_rrr_bf16<<<dim3(DIM_ / 128, NTOK_ / 128), blk, 0, stream>>>(ab, wo, out, NTOK_, DIM_, DIM_);
}

// Round 2
// 1125.937 us; speedup vs baseline: 2.2436x; 2.2436x over previous
//
#include <hip/hip_runtime.h>
#include <math.h>

#define BSZ_  4
#define SEQ_  1024
#define NH_   32
#define NKVH_ 8
#define HD_   128
#define DIM_  4096
#define NTOK_ (BSZ_ * SEQ_)   // 4096 tokens

typedef float  floatx4 __attribute__((ext_vector_type(4)));
typedef __bf16 bf16x8  __attribute__((ext_vector_type(8)));

__device__ __forceinline__ unsigned short f2bf_bits(float f) {
  unsigned int u = __float_as_uint(f);
  u += 0x7FFFu + ((u >> 16) & 1u);   // round-to-nearest-even
  return (unsigned short)(u >> 16);
}
__device__ __forceinline__ float bf2f(unsigned short b) {
  return __uint_as_float(((unsigned int)b) << 16);
}

// async global->LDS, 16B per lane; LDS dest = wave-uniform base + lane*16
__device__ __forceinline__ void gld16(const void* g, void* l) {
  __builtin_amdgcn_global_load_lds(
      (const __attribute__((address_space(1))) void*)g,
      (__attribute__((address_space(3))) void*)l, 16, 0, 0);
}

// ---------------------------------------------------------------------------
// fp32 -> bf16 convert (contiguous). n must be multiple of 1024.
// ---------------------------------------------------------------------------
__global__ __launch_bounds__(256)
void xconv(const float* __restrict__ X, unsigned short* __restrict__ XB)
{
  size_t i = ((size_t)blockIdx.x * 256 + threadIdx.x) * 4;
  float4 v = *(const float4*)&X[i];
  ushort4 o;
  o.x = f2bf_bits(v.x); o.y = f2bf_bits(v.y);
  o.z = f2bf_bits(v.z); o.w = f2bf_bits(v.w);
  *(ushort4*)&XB[i] = o;
}

// ---------------------------------------------------------------------------
// Weight transpose-convert: W[K][N] fp32 -> WT[N][K] bf16. 32x32 tiles.
// grid = (N/32, K/32)
// ---------------------------------------------------------------------------
__global__ __launch_bounds__(256)
void wtrans(const float* __restrict__ W, unsigned short* __restrict__ WT,
            int K, int N)
{
  __shared__ unsigned short T[32][36];
  const int k0 = blockIdx.y * 32, n0 = blockIdx.x * 32;
  const int t = threadIdx.x;
  {
    int kr = t >> 3, nc = (t & 7) * 4;
    float4 v = *(const float4*)&W[(size_t)(k0 + kr) * N + n0 + nc];
    T[kr][nc + 0] = f2bf_bits(v.x);
    T[kr][nc + 1] = f2bf_bits(v.y);
    T[kr][nc + 2] = f2bf_bits(v.z);
    T[kr][nc + 3] = f2bf_bits(v.w);
  }
  __syncthreads();
  {
    int nr = t >> 3, kc = (t & 7) * 4;
    ushort4 o;
    o.x = T[kc + 0][nr]; o.y = T[kc + 1][nr];
    o.z = T[kc + 2][nr]; o.w = T[kc + 3][nr];
    *(ushort4*)&WT[(size_t)(n0 + nr) * K + k0 + kc] = o;
  }
}

// ---------------------------------------------------------------------------
// V transpose bf16: V[b][s][8][128] -> VT[b][8][128][1024]. 32x32 tiles.
// grid = (SEQ/32, HD/32, BSZ*NKVH)
// ---------------------------------------------------------------------------
__global__ __launch_bounds__(256)
void vtrans(const unsigned short* __restrict__ V, unsigned short* __restrict__ VT)
{
  __shared__ unsigned short T[32][36];
  const int bh = blockIdx.z;                 // b*8+kvh
  const int s0 = blockIdx.x * 32, d0 = blockIdx.y * 32;
  const int b = bh >> 3, kvh = bh & 7;
  const int t = threadIdx.x;
  {
    int sr = t >> 3, dc = (t & 7) * 4;
    ushort4 v = *(const ushort4*)&V[(((size_t)b * SEQ_ + s0 + sr) * NKVH_ + kvh) * HD_ + d0 + dc];
    T[sr][dc + 0] = v.x; T[sr][dc + 1] = v.y;
    T[sr][dc + 2] = v.z; T[sr][dc + 3] = v.w;
  }
  __syncthreads();
  {
    int dr = t >> 3, sc = (t & 7) * 4;
    ushort4 o;
    o.x = T[sc + 0][dr]; o.y = T[sc + 1][dr];
    o.z = T[sc + 2][dr]; o.w = T[sc + 3][dr];
    *(ushort4*)&VT[((size_t)bh * HD_ + d0 + dr) * SEQ_ + s0 + sc] = o;
  }
}

// ---------------------------------------------------------------------------
// RoPE in place on bf16 (B,S,nh,128): one thread per even/odd pair (u32).
// ---------------------------------------------------------------------------
__global__ __launch_bounds__(256)
void rope_bf16(unsigned int* __restrict__ t, const float* __restrict__ cosf,
               const float* __restrict__ sinf, int shift)
{
  int idx = blockIdx.x * 256 + threadIdx.x;
  int d2  = idx & 63;
  int pos = (idx >> shift) & (SEQ_ - 1);
  unsigned int p = t[idx];
  float xe = __uint_as_float(p << 16);
  float xo = __uint_as_float(p & 0xFFFF0000u);
  float cv = cosf[pos * 64 + d2];
  float sv = sinf[pos * 64 + d2];
  float oe = xe * cv - xo * sv;
  float oo = xe * sv + xo * cv;
  t[idx] = (unsigned int)f2bf_bits(oe) | ((unsigned int)f2bf_bits(oo) << 16);
}

// ---------------------------------------------------------------------------
// m97-style GEMM: C[M][N] = A[M][K] @ B^T (B stored [N][K]), bf16 in, 
// bf16 or fp32 out. Tile 128x128x32, 4 waves x (64x64), global_load_lds w=16.
// ---------------------------------------------------------------------------
template<bool OUT_BF16>
__global__ __launch_bounds__(256)
void gemm_bt(const unsigned short* __restrict__ A,   // [M][K] bf16
             const unsigned short* __restrict__ B,   // [N][K] bf16
             void* __restrict__ Cout, int M, int N, int K)
{
  __shared__ __align__(16) unsigned short As[128][32];
  __shared__ __align__(16) unsigned short Bs[128][32];

  const int tid  = threadIdx.x;
  const int bm   = blockIdx.y * 128;
  const int bn   = blockIdx.x * 128;
  const int w    = tid >> 6;
  const int lane = tid & 63;
  const int l16  = lane & 15;
  const int quad = lane >> 4;
  const int mw   = (w >> 1) * 64;
  const int nw   = (w & 1) * 64;
  const int lrow   = lane >> 2;          // 16 rows per 1KB wave-load
  const int lchunk = (lane & 3) * 8;     // 8 bf16 (16B) chunks along k

  floatx4 acc[4][4];
#pragma unroll
  for (int i = 0; i < 4; i++)
#pragma unroll
    for (int j = 0; j < 4; j++) acc[i][j] = (floatx4){0.f, 0.f, 0.f, 0.f};

  for (int k0 = 0; k0 < K; k0 += 32) {
#pragma unroll
    for (int l = 0; l < 2; l++) {
      int r = (w * 2 + l) * 16 + lrow;
      gld16(&A[(size_t)(bm + r) * K + k0 + lchunk], &As[(w * 2 + l) * 16][0]);
      gld16(&B[(size_t)(bn + r) * K + k0 + lchunk], &Bs[(w * 2 + l) * 16][0]);
    }
    __syncthreads();

    bf16x8 af[4], bfr[4];
#pragma unroll
    for (int i = 0; i < 4; i++)
      af[i] = *(const bf16x8*)&As[mw + i * 16 + l16][quad * 8];
#pragma unroll
    for (int j = 0; j < 4; j++)
      bfr[j] = *(const bf16x8*)&Bs[nw + j * 16 + l16][quad * 8];
#pragma unroll
    for (int i = 0; i < 4; i++)
#pragma unroll
      for (int j = 0; j < 4; j++)
        acc[i][j] = __builtin_amdgcn_mfma_f32_16x16x32_bf16(af[i], bfr[j], acc[i][j], 0, 0, 0);
    __syncthreads();
  }

#pragma unroll
  for (int i = 0; i < 4; i++)
#pragma unroll
    for (int j = 0; j < 4; j++)
#pragma unroll
      for (int r = 0; r < 4; r++) {
        size_t row = bm + mw + i * 16 + quad * 4 + r;
        size_t col = bn + nw + j * 16 + l16;
        if (OUT_BF16)
          ((unsigned short*)Cout)[row * N + col] = f2bf_bits(acc[i][j][r]);
        else
          ((float*)Cout)[row * N + col] = acc[i][j][r];
      }
}

// ---------------------------------------------------------------------------
// Flash attention (GQA, causal), all-bf16 operands.
// q: [b][s][32][128] bf16 (RoPE'd)   k: [b][s][8][128] bf16 (RoPE'd)
// vt: [b][8][128][1024] bf16 (pre-transposed)   o: [b][s][32][128] bf16
// Block = 64 q-rows of one (b,h); 4 waves x 16 q-rows; K-tiles of 32 keys.
// ---------------------------------------------------------------------------
__global__ __launch_bounds__(256)
void flash_attn(const unsigned short* __restrict__ q,
                const unsigned short* __restrict__ k,
                const unsigned short* __restrict__ vt,
                unsigned short* __restrict__ o)
{
  const int qt  = blockIdx.x;
  const int h   = blockIdx.y;
  const int b   = blockIdx.z;
  const int kvh = h >> 2;
  const int tid  = threadIdx.x;
  const int w    = tid >> 6;
  const int lane = tid & 63;
  const int l16  = lane & 15;
  const int quad = lane >> 4;
  const int q0   = qt * 64;
  const int qrow_base = q0 + w * 16;

  __shared__ __align__(16) unsigned short Ks[32][128];   // [key][d]
  __shared__ __align__(16) unsigned short VtS[128][32];  // [d][key]
  __shared__ __align__(16) unsigned short Ps[4][16][32]; // per-wave P

  const float SCALE = 0.08838834764831845f; // 1/sqrt(128)

  // Q fragments: qf[c] = Q[qrow_base+l16][c*32 + quad*8 .. +7]
  bf16x8 qf[4];
  {
    const unsigned short* qrow = &q[(((size_t)b * SEQ_ + qrow_base + l16) * NH_ + h) * HD_];
#pragma unroll
    for (int c = 0; c < 4; c++)
      qf[c] = *(const bf16x8*)&qrow[c * 32 + quad * 8];
  }

  float m_r[4], l_r[4];
  floatx4 oacc[8];
#pragma unroll
  for (int r = 0; r < 4; r++) { m_r[r] = -3.0e38f; l_r[r] = 0.f; }
#pragma unroll
  for (int dt = 0; dt < 8; dt++) oacc[dt] = (floatx4){0.f, 0.f, 0.f, 0.f};

  const int krow   = lane >> 4;          // K-tile: 4 rows per 1KB wave-load
  const int kchunk = (lane & 15) * 8;
  const int vrow   = lane >> 2;          // V-tile: 16 rows per wave-load
  const int vchunk = (lane & 3) * 8;

  const int ktiles = (q0 + 64) >> 5;
  for (int kt = 0; kt < ktiles; kt++) {
    const int kbase = kt * 32;
#pragma unroll
    for (int l = 0; l < 2; l++) {
      int key = (w * 2 + l) * 4 + krow;
      gld16(&k[(((size_t)b * SEQ_ + kbase + key) * NKVH_ + kvh) * HD_ + kchunk],
            &Ks[(w * 2 + l) * 4][0]);
      int d0 = (w * 2 + l) * 16 + vrow;
      gld16(&vt[(((size_t)b * NKVH_ + kvh) * HD_ + d0) * SEQ_ + kbase + vchunk],
            &VtS[(w * 2 + l) * 16][0]);
    }
    __syncthreads();

    // QK^T
    floatx4 sc0 = (floatx4){0.f, 0.f, 0.f, 0.f};
    floatx4 sc1 = (floatx4){0.f, 0.f, 0.f, 0.f};
#pragma unroll
    for (int c = 0; c < 4; c++) {
      bf16x8 b0 = *(const bf16x8*)&Ks[l16][c * 32 + quad * 8];
      bf16x8 b1 = *(const bf16x8*)&Ks[16 + l16][c * 32 + quad * 8];
      sc0 = __builtin_amdgcn_mfma_f32_16x16x32_bf16(qf[c], b0, sc0, 0, 0, 0);
      sc1 = __builtin_amdgcn_mfma_f32_16x16x32_bf16(qf[c], b1, sc1, 0, 0, 0);
    }

    // online softmax per q-row
#pragma unroll
    for (int r = 0; r < 4; r++) {
      int qi = qrow_base + quad * 4 + r;
      float s0 = (kbase + l16      <= qi) ? sc0[r] * SCALE : -3.0e38f;
      float s1 = (kbase + 16 + l16 <= qi) ? sc1[r] * SCALE : -3.0e38f;
      float mx = fmaxf(s0, s1);
      mx = fmaxf(mx, __shfl_xor(mx, 1));
      mx = fmaxf(mx, __shfl_xor(mx, 2));
      mx = fmaxf(mx, __shfl_xor(mx, 4));
      mx = fmaxf(mx, __shfl_xor(mx, 8));
      float mnew  = fmaxf(m_r[r], mx);
      float alpha = __expf(m_r[r] - mnew);
      float p0    = __expf(s0 - mnew);
      float p1    = __expf(s1 - mnew);
      float rs = p0 + p1;
      rs += __shfl_xor(rs, 1);
      rs += __shfl_xor(rs, 2);
      rs += __shfl_xor(rs, 4);
      rs += __shfl_xor(rs, 8);
      l_r[r] = l_r[r] * alpha + rs;
      m_r[r] = mnew;
#pragma unroll
      for (int dt = 0; dt < 8; dt++) oacc[dt][r] *= alpha;
      Ps[w][quad * 4 + r][l16]      = f2bf_bits(p0);
      Ps[w][quad * 4 + r][16 + l16] = f2bf_bits(p1);
    }

    // PV
    bf16x8 pf = *(const bf16x8*)&Ps[w][l16][quad * 8];
#pragma unroll
    for (int dt = 0; dt < 8; dt++) {
      bf16x8 vf = *(const bf16x8*)&VtS[dt * 16 + l16][quad * 8];
      oacc[dt] = __builtin_amdgcn_mfma_f32_16x16x32_bf16(pf, vf, oacc[dt], 0, 0, 0);
    }
    __syncthreads();
  }

  // normalize + write bf16
#pragma unroll
  for (int r = 0; r < 4; r++) {
    float inv = 1.0f / l_r[r];
    int qi = qrow_base + quad * 4 + r;
    unsigned short* orow = &o[(((size_t)b * SEQ_ + qi) * NH_ + h) * HD_];
#pragma unroll
    for (int dt = 0; dt < 8; dt++)
      orow[dt * 16 + l16] = f2bf_bits(oacc[dt][r] * inv);
  }
}

// ---------------------------------------------------------------------------
extern "C" void kernel_launch(void* const* d_in, const int* in_sizes, int n_in,
                              void* d_out, int out_size, void* d_ws, size_t ws_size,
                              hipStream_t stream)
{
  const float* x  = (const float*)d_in[0];
  const float* wq = (const float*)d_in[1];
  const float* wk = (const float*)d_in[2];
  const float* wv = (const float*)d_in[3];
  const float* wo = (const float*)d_in[4];
  const float* fc = (const float*)d_in[5];
  const float* fs = (const float*)d_in[6];
  float* out = (float*)d_out;

  // bf16 workspace layout (2B elems)
  unsigned short* xb  = (unsigned short*)d_ws;             // 16M  (32MB) -> reused as ab
  unsigned short* wqT = xb  + (size_t)DIM_ * DIM_;         // 16M  (32MB) -> reused as woT
  unsigned short* wkT = wqT + (size_t)DIM_ * DIM_;         // 4M   (8MB)
  unsigned short* wvT = wkT + (size_t)DIM_ * NKVH_ * HD_;  // 4M   (8MB)
  unsigned short* qb  = wvT + (size_t)DIM_ * NKVH_ * HD_;  // 16M  (32MB)
  unsigned short* kb  = qb  + (size_t)NTOK_ * DIM_;        // 4M   (8MB)
  unsigned short* vb  = kb  + (size_t)NTOK_ * NKVH_ * HD_; // 4M   (8MB)
  unsigned short* vt  = vb  + (size_t)NTOK_ * NKVH_ * HD_; // 4M   (8MB)
  unsigned short* ab  = xb;   // alias: xb dead after V-proj
  unsigned short* woT = wqT;  // alias: wqT dead after Q-proj

  dim3 blk(256);

  xconv<<<(NTOK_ * DIM_ / 4) / 256, blk, 0, stream>>>(x, xb);
  wtrans<<<dim3(DIM_ / 32, DIM_ / 32), blk, 0, stream>>>(wq, wqT, DIM_, DIM_);
  wtrans<<<dim3((NKVH_ * HD_) / 32, DIM_ / 32), blk, 0, stream>>>(wk, wkT, DIM_, NKVH_ * HD_);
  wtrans<<<dim3((NKVH_ * HD_) / 32, DIM_ / 32), blk, 0, stream>>>(wv, wvT, DIM_, NKVH_ * HD_);

  gemm_bt<true><<<dim3(DIM_ / 128, NTOK_ / 128), blk, 0, stream>>>(xb, wqT, qb, NTOK_, DIM_, DIM_);
  wtrans<<<dim3(DIM_ / 32, DIM_ / 32), blk, 0, stream>>>(wo, woT, DIM_, DIM_);  // after Q-proj (aliases wqT)
  gemm_bt<true><<<dim3((NKVH_ * HD_) / 128, NTOK_ / 128), blk, 0, stream>>>(xb, wkT, kb, NTOK_, NKVH_ * HD_, DIM_);
  gemm_bt<true><<<dim3((NKVH_ * HD_) / 128, NTOK_ / 128), blk, 0, stream>>>(xb, wvT, vb, NTOK_, NKVH_ * HD_, DIM_);

  rope_bf16<<<(NTOK_ * NH_ * HD_ / 2) / 256, blk, 0, stream>>>((unsigned int*)qb, fc, fs, 11);
  rope_bf16<<<(NTOK_ * NKVH_ * HD_ / 2) / 256, blk, 0, stream>>>((unsigned int*)kb, fc, fs, 9);

  vtrans<<<dim3(SEQ_ / 32, HD_ / 32, BSZ_ * NKVH_), blk, 0, stream>>>(vb, vt);

  flash_attn<<<dim3(SEQ_ / 64, NH_, BSZ_), blk, 0, stream>>>(qb, kb, vt, ab);

  gemm_bt<false><<<dim3(DIM_ / 128, NTOK_ / 128), blk, 0, stream>>>(ab, woT, out, NTOK_, DIM_, DIM_);
}

// Round 4
// 871.903 us; speedup vs baseline: 2.8973x; 1.2914x over previous
//
#include <hip/hip_runtime.h>

#define BSZ_  4
#define SEQ_  1024
#define NH_   32
#define NKVH_ 8
#define HD_   128
#define DIM_  4096
#define NTOK_ (BSZ_ * SEQ_)   // 4096 tokens
#define QKVW_ 6144            // fused QKV output width (u16 elems per token)

typedef float  floatx4  __attribute__((ext_vector_type(4)));
typedef float  floatx16 __attribute__((ext_vector_type(16)));
typedef __bf16 bf16x8   __attribute__((ext_vector_type(8)));
typedef unsigned short ushortx8 __attribute__((ext_vector_type(8)));

__device__ __forceinline__ float fast_exp2(float x) {
  return __builtin_amdgcn_exp2f(x);   // v_exp_f32 (computes 2^x natively)
}

__device__ __forceinline__ unsigned short f2bf_bits(float f) {
  unsigned int u = __float_as_uint(f);
  u += 0x7FFFu + ((u >> 16) & 1u);   // round-to-nearest-even
  return (unsigned short)(u >> 16);
}
__device__ __forceinline__ unsigned int pack_bf2_rne(float lo, float hi_) {
  return (unsigned int)f2bf_bits(lo) | ((unsigned int)f2bf_bits(hi_) << 16);
}
// truncating pack of two fp32 -> bf16x2 (one v_perm_b32)
__device__ __forceinline__ unsigned int pack_bf2_trunc(float lo, float hi_) {
  return __builtin_amdgcn_perm(__float_as_uint(hi_), __float_as_uint(lo), 0x07060302u);
}

// async global->LDS, 16B per lane; LDS dest = wave-uniform base + lane*16
__device__ __forceinline__ void gld16(const void* g, void* l) {
  __builtin_amdgcn_global_load_lds(
      (const __attribute__((address_space(1))) void*)g,
      (__attribute__((address_space(3))) void*)l, 16, 0, 0);
}

// ---------------------------------------------------------------------------
// fp32 -> bf16 convert (contiguous).
// ---------------------------------------------------------------------------
__global__ __launch_bounds__(256)
void xconv(const float* __restrict__ X, unsigned short* __restrict__ XB)
{
  size_t i = ((size_t)blockIdx.x * 256 + threadIdx.x) * 4;
  float4 v = *(const float4*)&X[i];
  ushort4 o;
  o.x = f2bf_bits(v.x); o.y = f2bf_bits(v.y);
  o.z = f2bf_bits(v.z); o.w = f2bf_bits(v.w);
  *(ushort4*)&XB[i] = o;
}

// ---------------------------------------------------------------------------
// Weight transpose-convert: W[K][N] fp32 -> WT[N][K] bf16. 32x32 tiles.
// ---------------------------------------------------------------------------
__global__ __launch_bounds__(256)
void wtrans(const float* __restrict__ W, unsigned short* __restrict__ WT,
            int K, int N)
{
  __shared__ unsigned short T[32][36];
  const int k0 = blockIdx.y * 32, n0 = blockIdx.x * 32;
  const int t = threadIdx.x;
  {
    int kr = t >> 3, nc = (t & 7) * 4;
    float4 v = *(const float4*)&W[(size_t)(k0 + kr) * N + n0 + nc];
    T[kr][nc + 0] = f2bf_bits(v.x);
    T[kr][nc + 1] = f2bf_bits(v.y);
    T[kr][nc + 2] = f2bf_bits(v.z);
    T[kr][nc + 3] = f2bf_bits(v.w);
  }
  __syncthreads();
  {
    int nr = t >> 3, kc = (t & 7) * 4;
    ushort4 o;
    o.x = T[kc + 0][nr]; o.y = T[kc + 1][nr];
    o.z = T[kc + 2][nr]; o.w = T[kc + 3][nr];
    *(ushort4*)&WT[(size_t)(n0 + nr) * K + k0 + kc] = o;
  }
}

// ---------------------------------------------------------------------------
// V transpose from fused qkv buffer: qkv[tok][5120 + kvh*128 + d] ->
// VT[(b*8+kvh)*128 + d][1024 s]. 32x32 tiles. grid = (SEQ/32, HD/32, B*NKVH)
// ---------------------------------------------------------------------------
__global__ __launch_bounds__(256)
void vtrans2(const unsigned short* __restrict__ qkv, unsigned short* __restrict__ VT)
{
  __shared__ unsigned short T[32][36];
  const int bh = blockIdx.z;                 // b*8+kvh
  const int s0 = blockIdx.x * 32, d0 = blockIdx.y * 32;
  const int b = bh >> 3, kvh = bh & 7;
  const int t = threadIdx.x;
  {
    int sr = t >> 3, dc = (t & 7) * 4;
    ushort4 v = *(const ushort4*)&qkv[(size_t)(b * SEQ_ + s0 + sr) * QKVW_ + 5120 + kvh * HD_ + d0 + dc];
    T[sr][dc + 0] = v.x; T[sr][dc + 1] = v.y;
    T[sr][dc + 2] = v.z; T[sr][dc + 3] = v.w;
  }
  __syncthreads();
  {
    int dr = t >> 3, sc = (t & 7) * 4;
    ushort4 o;
    o.x = T[sc + 0][dr]; o.y = T[sc + 1][dr];
    o.z = T[sc + 2][dr]; o.w = T[sc + 3][dr];
    *(ushort4*)&VT[((size_t)bh * HD_ + d0 + dr) * SEQ_ + s0 + sc] = o;
  }
}

// ---------------------------------------------------------------------------
// RoPE in place on bf16 pairs inside the fused qkv buffer.
// idx covers NTOK_ * (per_tok pairs); per_tok = 1<<shift.
// u32 address = tok*stride + base + (idx & (per_tok-1)).
// ---------------------------------------------------------------------------
__global__ __launch_bounds__(256)
void rope2(unsigned int* __restrict__ t, const float* __restrict__ cosf,
           const float* __restrict__ sinf, int shift, int stride_u32, int base_u32)
{
  int idx = blockIdx.x * 256 + threadIdx.x;
  int tok = idx >> shift;
  int rem = idx & ((1 << shift) - 1);
  int d2  = idx & 63;
  int pos = tok & (SEQ_ - 1);
  unsigned int* p = &t[(size_t)tok * stride_u32 + base_u32 + rem];
  unsigned int pv = *p;
  float xe = __uint_as_float(pv << 16);
  float xo = __uint_as_float(pv & 0xFFFF0000u);
  float cv = cosf[pos * 64 + d2];
  float sv = sinf[pos * 64 + d2];
  float oe = xe * cv - xo * sv;
  float oo = xe * sv + xo * cv;
  *p = pack_bf2_rne(oe, oo);
}

// ---------------------------------------------------------------------------
// m97-style GEMM: C[M][N] = A[M][K] @ B^T (B stored [N][K]), bf16 in,
// bf16 or fp32 out. Tile 128x128x32, 4 waves x (64x64), global_load_lds w=16.
// ---------------------------------------------------------------------------
template<bool OUT_BF16>
__global__ __launch_bounds__(256)
void gemm_bt(const unsigned short* __restrict__ A,   // [M][K] bf16
             const unsigned short* __restrict__ B,   // [N][K] bf16
             void* __restrict__ Cout, int M, int N, int K)
{
  __shared__ __align__(16) unsigned short As[128][32];
  __shared__ __align__(16) unsigned short Bs[128][32];

  const int tid  = threadIdx.x;
  const int bm   = blockIdx.y * 128;
  const int bn   = blockIdx.x * 128;
  const int w    = tid >> 6;
  const int lane = tid & 63;
  const int l16  = lane & 15;
  const int quad = lane >> 4;
  const int mw   = (w >> 1) * 64;
  const int nw   = (w & 1) * 64;
  const int lrow   = lane >> 2;
  const int lchunk = (lane & 3) * 8;

  floatx4 acc[4][4];
#pragma unroll
  for (int i = 0; i < 4; i++)
#pragma unroll
    for (int j = 0; j < 4; j++) acc[i][j] = (floatx4){0.f, 0.f, 0.f, 0.f};

  for (int k0 = 0; k0 < K; k0 += 32) {
#pragma unroll
    for (int l = 0; l < 2; l++) {
      int r = (w * 2 + l) * 16 + lrow;
      gld16(&A[(size_t)(bm + r) * K + k0 + lchunk], &As[(w * 2 + l) * 16][0]);
      gld16(&B[(size_t)(bn + r) * K + k0 + lchunk], &Bs[(w * 2 + l) * 16][0]);
    }
    __syncthreads();

    bf16x8 af[4], bfr[4];
#pragma unroll
    for (int i = 0; i < 4; i++)
      af[i] = *(const bf16x8*)&As[mw + i * 16 + l16][quad * 8];
#pragma unroll
    for (int j = 0; j < 4; j++)
      bfr[j] = *(const bf16x8*)&Bs[nw + j * 16 + l16][quad * 8];
#pragma unroll
    for (int i = 0; i < 4; i++)
#pragma unroll
      for (int j = 0; j < 4; j++)
        acc[i][j] = __builtin_amdgcn_mfma_f32_16x16x32_bf16(af[i], bfr[j], acc[i][j], 0, 0, 0);
    __syncthreads();
  }

#pragma unroll
  for (int i = 0; i < 4; i++)
#pragma unroll
    for (int j = 0; j < 4; j++)
#pragma unroll
      for (int r = 0; r < 4; r++) {
        size_t row = bm + mw + i * 16 + quad * 4 + r;
        size_t col = bn + nw + j * 16 + l16;
        if (OUT_BF16)
          ((unsigned short*)Cout)[row * N + col] = f2bf_bits(acc[i][j][r]);
        else
          ((float*)Cout)[row * N + col] = acc[i][j][r];
      }
}

// ---------------------------------------------------------------------------
// Flash attention v2 (GQA, causal): S^T = K Q^T via mfma_32x32x16 so softmax
// is per-lane-column; O^T = V^T P^T. All LDS XOR-chunk-swizzled (conflict-free).
// Block = 256 q of one (b,h); 4 waves x 64 q; K-tiles of 64 keys.
// qkv: fused bf16 [tok][6144] (Q at 0, K at 4096, RoPE'd)
// vt:  bf16 [(b*8+kvh)*128 + d][1024]
// o:   bf16 [tok][4096]
// ---------------------------------------------------------------------------
__global__ __launch_bounds__(256, 2)
void flash_attn2(const unsigned short* __restrict__ qkv,
                 const unsigned short* __restrict__ vt,
                 unsigned short* __restrict__ o)
{
  __shared__ __align__(16) unsigned short S_[4][8192];  // 64 KiB total
  unsigned short* Ks = &S_[0][0];            // [64 key][128 d], chunk-swizzled ^ (key&15)
  unsigned short* Vs = &S_[1][0];            // [128 d][64 key], chunk-swizzled ^ (d&7)
  // Ps per wave: S_[2..3], 4096 u16 each:   [64 q][64 key], chunk-swizzled ^ (q&7)

  const int qt = blockIdx.x, h = blockIdx.y, b = blockIdx.z;
  const int kvh = h >> 2;
  const int tid = threadIdx.x, w = tid >> 6, lane = tid & 63;
  const int l31 = lane & 31, hi = lane >> 5;
  const int qb = qt * 256, qw = qb + w * 64;
  unsigned short* Ps = &S_[2][0] + w * 4096;

  const float CEXP = (float)(0.08838834764831845 * 1.4426950408889634); // scale*log2(e)

  // ---- Q fragments in registers (B-operand layout: n=l31, k=hi*8+j per 16-k step)
  bf16x8 qf[2][8];
#pragma unroll
  for (int t2 = 0; t2 < 2; t2++) {
    const unsigned short* qrow =
        &qkv[(size_t)(b * SEQ_ + qw + t2 * 32 + l31) * QKVW_ + h * HD_ + hi * 8];
#pragma unroll
    for (int s = 0; s < 8; s++)
      qf[t2][s] = *(const bf16x8*)&qrow[s * 16];
  }

  floatx16 oa[2][4];   // O^T accumulators: [q-subtile][d-tile], col=q=l31
#pragma unroll
  for (int t2 = 0; t2 < 2; t2++)
#pragma unroll
    for (int dt = 0; dt < 4; dt++)
#pragma unroll
      for (int r = 0; r < 16; r++) oa[t2][dt][r] = 0.f;

  float ms[2] = {-3.0e38f, -3.0e38f};  // running max, SCALED (log2) units
  float ls[2] = {0.f, 0.f};

  const int nk = qb + 256;
  const int qmaxw = qw + 63;

  for (int kb_ = 0; kb_ < nk; kb_ += 64) {
    __syncthreads();   // protect LDS from previous iteration's readers
    // ---- stage K tile: 64 keys x 128 d (16 chunks/row)
    {
      const size_t gbase = (size_t)(b * SEQ_ + kb_) * QKVW_ + 4096 + kvh * HD_;
#pragma unroll
      for (int it = 0; it < 4; it++) {
        int idx = it * 256 + tid;
        int key = idx >> 4, c = idx & 15;
        ushortx8 vld = *(const ushortx8*)&qkv[gbase + (size_t)key * QKVW_ + c * 8];
        *(ushortx8*)&Ks[key * 128 + ((c ^ (key & 15)) * 8)] = vld;
      }
      // ---- stage V^T tile: 128 d x 64 keys (8 chunks/row)
      const size_t vbase = ((size_t)(b * NKVH_ + kvh) * HD_) * SEQ_ + kb_;
#pragma unroll
      for (int it = 0; it < 4; it++) {
        int idx = it * 256 + tid;
        int d = idx >> 3, c = idx & 7;
        ushortx8 vld = *(const ushortx8*)&vt[vbase + (size_t)d * SEQ_ + c * 8];
        *(ushortx8*)&Vs[d * 64 + ((c ^ (d & 7)) * 8)] = vld;
      }
    }
    __syncthreads();

    if (kb_ <= qmaxw) {                      // wave has >=1 unmasked key in tile
      const bool needmask = (kb_ + 63 > qw);

#pragma unroll
      for (int t2 = 0; t2 < 2; t2++) {
        // ---- S^T = K @ Q^T : two 32-key C-tiles, rows=keys, cols=queries
        floatx16 sc[2];
#pragma unroll
        for (int r = 0; r < 16; r++) { sc[0][r] = 0.f; sc[1][r] = 0.f; }
#pragma unroll
        for (int s = 0; s < 8; s++) {
          int c = 2 * s + hi;
          bf16x8 k0 = *(const bf16x8*)&Ks[l31 * 128 + ((c ^ (l31 & 15)) * 8)];
          bf16x8 k1 = *(const bf16x8*)&Ks[(32 + l31) * 128 + ((c ^ ((32 + l31) & 15)) * 8)];
          sc[0] = __builtin_amdgcn_mfma_f32_32x32x16_bf16(k0, qf[t2][s], sc[0], 0, 0, 0);
          sc[1] = __builtin_amdgcn_mfma_f32_32x32x16_bf16(k1, qf[t2][s], sc[1], 0, 0, 0);
        }

        // ---- causal mask (row = key = (r&3)+8*(r>>2)+4*hi; col = q = l31)
        if (needmask) {
          const int q = qw + t2 * 32 + l31;
#pragma unroll
          for (int k2 = 0; k2 < 2; k2++)
#pragma unroll
            for (int r = 0; r < 16; r++) {
              int key = kb_ + k2 * 32 + (r & 3) + 8 * (r >> 2) + 4 * hi;
              if (key > q) sc[k2][r] = -3.0e38f;
            }
        }

        // ---- online softmax for this lane's query (32 vals in-lane + xor32)
        float mx0 = sc[0][0], mx1 = sc[0][1];
#pragma unroll
        for (int r = 2; r < 16; r += 2) { mx0 = fmaxf(mx0, sc[0][r]); mx1 = fmaxf(mx1, sc[0][r + 1]); }
#pragma unroll
        for (int r = 0; r < 16; r += 2) { mx0 = fmaxf(mx0, sc[1][r]); mx1 = fmaxf(mx1, sc[1][r + 1]); }
        float mx = fmaxf(mx0, mx1);
        mx = fmaxf(mx, __shfl_xor(mx, 32));
        float mxs = mx * CEXP;
        float mn = fmaxf(ms[t2], mxs);
        float alpha = fast_exp2(ms[t2] - mn);
        ms[t2] = mn;

        float rs0 = 0.f, rs1 = 0.f;
        const int qloc = t2 * 32 + l31;
#pragma unroll
        for (int k2 = 0; k2 < 2; k2++) {
          unsigned int pk[8];
#pragma unroll
          for (int r = 0; r < 16; r += 2) {
            float p0 = fast_exp2(__builtin_fmaf(sc[k2][r],     CEXP, -mn));
            float p1 = fast_exp2(__builtin_fmaf(sc[k2][r + 1], CEXP, -mn));
            rs0 += p0; rs1 += p1;
            pk[r >> 1] = pack_bf2_trunc(p0, p1);
          }
#pragma unroll
          for (int rq = 0; rq < 4; rq++) {
            int keyoff = k2 * 32 + 8 * rq + 4 * hi;
            int c = keyoff >> 3;
            uint2 val = {pk[rq * 2], pk[rq * 2 + 1]};
            *(uint2*)&Ps[qloc * 64 + ((c ^ (qloc & 7)) * 8) + (keyoff & 7)] = val;
          }
        }
        float rs = rs0 + rs1;
        rs += __shfl_xor(rs, 32);
        ls[t2] = ls[t2] * alpha + rs;

        if (__any(alpha != 1.0f)) {
#pragma unroll
          for (int dt = 0; dt < 4; dt++)
#pragma unroll
            for (int r = 0; r < 16; r++) oa[t2][dt][r] *= alpha;
        }
      }

      // ---- O^T += V^T @ P^T  (A-frag V reused across both q-subtiles)
#pragma unroll
      for (int ks = 0; ks < 4; ks++) {
        int c = 2 * ks + hi;
        bf16x8 pf0, pf1;
        {
          int q0l = l31;
          int q1l = 32 + l31;
          pf0 = *(const bf16x8*)&Ps[q0l * 64 + ((c ^ (q0l & 7)) * 8)];
          pf1 = *(const bf16x8*)&Ps[q1l * 64 + ((c ^ (q1l & 7)) * 8)];
        }
#pragma unroll
        for (int dt = 0; dt < 4; dt++) {
          int d = dt * 32 + l31;
          bf16x8 vf = *(const bf16x8*)&Vs[d * 64 + ((c ^ (d & 7)) * 8)];
          oa[0][dt] = __builtin_amdgcn_mfma_f32_32x32x16_bf16(vf, pf0, oa[0][dt], 0, 0, 0);
          oa[1][dt] = __builtin_amdgcn_mfma_f32_32x32x16_bf16(vf, pf1, oa[1][dt], 0, 0, 0);
        }
      }
    }
  }

  // ---- epilogue: normalize, transpose O^T -> O rows via per-wave LDS patch
  __syncthreads();                 // everyone done reading Ks/Vs/Ps
  unsigned short* patch = &S_[w][0];   // [64 q][128 d], chunk-swizzled ^ (q&7)
  float inv[2] = {1.0f / ls[0], 1.0f / ls[1]};
#pragma unroll
  for (int t2 = 0; t2 < 2; t2++) {
    const int qloc = t2 * 32 + l31;
#pragma unroll
    for (int dt = 0; dt < 4; dt++)
#pragma unroll
      for (int rq = 0; rq < 4; rq++) {
        float a0 = oa[t2][dt][rq * 4 + 0] * inv[t2];
        float a1 = oa[t2][dt][rq * 4 + 1] * inv[t2];
        float a2 = oa[t2][dt][rq * 4 + 2] * inv[t2];
        float a3 = oa[t2][dt][rq * 4 + 3] * inv[t2];
        int doff = dt * 32 + 8 * rq + 4 * hi;
        int c = doff >> 3;
        uint2 val = {pack_bf2_rne(a0, a1), pack_bf2_rne(a2, a3)};
        *(uint2*)&patch[qloc * 128 + ((c ^ (qloc & 7)) * 8) + (doff & 7)] = val;
      }
  }
  // in-wave: write -> read dependency handled by compiler waitcnt
#pragma unroll
  for (int it = 0; it < 16; it++) {
    int idx = it * 64 + lane;
    int row = idx >> 4, c = idx & 15;
    int cc = (c & 7) ^ (row & 7);
    int cs = (c & 8) | cc;          // swizzle only low 3 bits (mask was &7)
    ushortx8 vv = *(const ushortx8*)&patch[row * 128 + cs * 8];
    *(ushortx8*)&o[(size_t)(b * SEQ_ + qb + w * 64 + row) * 4096 + h * HD_ + c * 8] = vv;
  }
}

// ---------------------------------------------------------------------------
extern "C" void kernel_launch(void* const* d_in, const int* in_sizes, int n_in,
                              void* d_out, int out_size, void* d_ws, size_t ws_size,
                              hipStream_t stream)
{
  const float* x  = (const float*)d_in[0];
  const float* wq = (const float*)d_in[1];
  const float* wk = (const float*)d_in[2];
  const float* wv = (const float*)d_in[3];
  const float* wo = (const float*)d_in[4];
  const float* fc = (const float*)d_in[5];
  const float* fs = (const float*)d_in[6];
  float* out = (float*)d_out;

  // bf16 workspace layout (2B elems): total 136 MB
  unsigned short* xb    = (unsigned short*)d_ws;                 // 4096x4096 (32MB), reused as ab
  unsigned short* wqkvT = xb    + (size_t)NTOK_ * DIM_;          // 6144x4096 (48MB), reused as woT
  unsigned short* qkvb  = wqkvT + (size_t)QKVW_ * DIM_;          // 4096x6144 (48MB)
  unsigned short* vtb   = qkvb  + (size_t)NTOK_ * QKVW_;         // 8x128x... (8MB)
  unsigned short* ab    = xb;    // alias: xb dead after QKV proj
  unsigned short* woT   = wqkvT; // alias: wqkvT dead after QKV proj

  dim3 blk(256);

  xconv<<<(NTOK_ * DIM_ / 4) / 256, blk, 0, stream>>>(x, xb);
  wtrans<<<dim3(DIM_ / 32, DIM_ / 32), blk, 0, stream>>>(wq, wqkvT, DIM_, DIM_);
  wtrans<<<dim3((NKVH_ * HD_) / 32, DIM_ / 32), blk, 0, stream>>>(wk, wqkvT + (size_t)4096 * DIM_, DIM_, NKVH_ * HD_);
  wtrans<<<dim3((NKVH_ * HD_) / 32, DIM_ / 32), blk, 0, stream>>>(wv, wqkvT + (size_t)5120 * DIM_, DIM_, NKVH_ * HD_);

  // fused QKV projection: [4096 tok][6144] bf16
  gemm_bt<true><<<dim3(QKVW_ / 128, NTOK_ / 128), blk, 0, stream>>>(xb, wqkvT, qkvb, NTOK_, QKVW_, DIM_);

  wtrans<<<dim3(DIM_ / 32, DIM_ / 32), blk, 0, stream>>>(wo, woT, DIM_, DIM_);  // aliases wqkvT: after QKV GEMM

  // RoPE on Q (2048 u32/token) and K (512 u32/token at base 2048)
  rope2<<<(NTOK_ * 2048) / 256, blk, 0, stream>>>((unsigned int*)qkvb, fc, fs, 11, 3072, 0);
  rope2<<<(NTOK_ * 512) / 256, blk, 0, stream>>>((unsigned int*)qkvb, fc, fs, 9, 3072, 2048);

  vtrans2<<<dim3(SEQ_ / 32, HD_ / 32, BSZ_ * NKVH_), blk, 0, stream>>>(qkvb, vtb);

  flash_attn2<<<dim3(SEQ_ / 256, NH_, BSZ_), blk, 0, stream>>>(qkvb, vtb, ab);

  gemm_bt<false><<<dim3(DIM_ / 128, NTOK_ / 128), blk, 0, stream>>>(ab, woT, out, NTOK_, DIM_, DIM_);
}